// Round 14
// baseline (177.009 us; speedup 1.0000x reference)
//
#include <hip/hip_runtime.h>
#include <hip/hip_bf16.h>
#include <stdint.h>

// Problem constants: B=2, S=2048, H=2048, HEAD_DIM=128, NUM_HEADS=16, NUM_KV=4
typedef __hip_bfloat16 bf16;
typedef __attribute__((ext_vector_type(8))) __bf16 bf16x8;
typedef __attribute__((ext_vector_type(4))) float f32x4;
typedef __attribute__((ext_vector_type(16))) float f32x16;
typedef __attribute__((ext_vector_type(4))) unsigned int u32x4;

// scale (1/sqrt(128)) * log2(e): folded into Q at RoPE time -> scores in log2 domain
#define QSCALE_LOG2E (0.08838834764831845f * 1.4426950408889634f)

__device__ __forceinline__ float fast_exp2(float x) {
#if __has_builtin(__builtin_amdgcn_exp2f)
  return __builtin_amdgcn_exp2f(x);
#else
  return exp2f(x);
#endif
}

// ---------------- async global->LDS (wave-uniform LDS base + lane*16) -------
__device__ __forceinline__ void gload_lds16(const void* g, void* l) {
  __builtin_amdgcn_global_load_lds(
      (__attribute__((address_space(1))) void*)(uintptr_t)g,
      (__attribute__((address_space(3))) void*)(uint32_t)(uintptr_t)l,
      16, 0, 0);
}

// ---------------- fused fp32 -> bf16 cast (hidden + w_qkv + w_o) -------------
__global__ void cast3(const float* __restrict__ h, const float* __restrict__ wq,
                      const float* __restrict__ wo, bf16* __restrict__ oh,
                      bf16* __restrict__ owq, bf16* __restrict__ owo) {
  const int total = 4718592;  // float4 chunks: 2097152 + 1572864 + 1048576
  const int stride = gridDim.x * blockDim.x;
  for (int c = blockIdx.x * blockDim.x + threadIdx.x; c < total; c += stride) {
    const float* src;
    bf16* dst;
    int i;
    if (c < 2097152) { src = h; dst = oh; i = c; }
    else if (c < 3670016) { src = wq; dst = owq; i = c - 2097152; }
    else { src = wo; dst = owo; i = c - 3670016; }
    float4 v = reinterpret_cast<const float4*>(src)[i];
    bf16 tmp[4];
    tmp[0] = __float2bfloat16(v.x);
    tmp[1] = __float2bfloat16(v.y);
    tmp[2] = __float2bfloat16(v.z);
    tmp[3] = __float2bfloat16(v.w);
    reinterpret_cast<uint2*>(dst)[i] = *reinterpret_cast<uint2*>(tmp);
  }
}

// ---------------- 256xBN deep-pipeline GEMM, 16 MFMA per phase ---------------
// BM=256, BN in {128,192}, BK=64, 512 threads = 8 waves (2M x 4N).
// Every phase holds exactly 16 MFMA (uniform amortization of barrier costs).
// BN=192: 3 phases/K-tile; A 3-buf staged 2 ahead, B 2-buf staged 1 ahead,
//         one vmcnt(4)/tile. BN=128: 2 phases/K-tile; A 3-buf + B 3-buf both
//         staged 2 ahead, one vmcnt(6)/tile. LDS = 144 KiB both.
__device__ __forceinline__ void store_c(float v, bf16* p) { *p = __float2bfloat16(v); }
__device__ __forceinline__ void store_c(float v, float* p) { *p = v; }

__device__ __forceinline__ bf16x8 rd_swz(const bf16* base, int row, int ks, int hi) {
  const int byte = row * 128 + ((ks * 64 + hi * 16) ^ ((row & 7) << 4));
  return *reinterpret_cast<const bf16x8*>((const char*)base + byte);
}

// stage granules [part*512, part*512+512) of a tile (rows x 64 cols) for K-step kt
__device__ __forceinline__ void stage_part(const bf16* __restrict__ g, int K,
                                           int kt, bf16* ldsBase, int part,
                                           int tid) {
  const int ga = part * 512 + tid;  // granule index within tile
  const int r = ga >> 3;            // row
  const int gl = ga & 7;            // 16B granule within row
  const int col = kt * 64 + ((gl ^ (r & 7)) << 3);
  gload_lds16(g + (size_t)r * K + col, (char*)ldsBase + ga * 16);
}

#define PHASE_SYNC_PRE()                                \
  __builtin_amdgcn_s_barrier();                         \
  asm volatile("s_waitcnt lgkmcnt(0)" ::: "memory");    \
  __builtin_amdgcn_sched_barrier(0);

#define PHASE_END() __builtin_amdgcn_s_barrier();

template <int BN, typename OutT>
__global__ __launch_bounds__(512, 2) void gemm_dp(const bf16* __restrict__ A,
                                                  const bf16* __restrict__ B,
                                                  OutT* __restrict__ C,
                                                  int M, int N, int K, int NBX) {
  constexpr int NFRAG = BN / 64;            // 2 or 3 n-frags per wave
  constexpr int WN = BN / 4;
  constexpr int LB = BN / 64;               // B stage parts per tile
  constexpr int NBB = (NFRAG == 2) ? 3 : 2; // B buffer count
  constexpr int AB = (NFRAG == 2) ? 2 : 1;  // B stage-ahead distance

  extern __shared__ bf16 sm[];
  bf16* Ab = sm;                 // 3 x [256][64] = 96 KiB
  bf16* Bb = sm + 3 * 16384;     // NBB x [BN][64]

  const int tid = threadIdx.x;
  const int lane = tid & 63;
  const int w = tid >> 6;
  const int wm = w >> 2;      // 0..1
  const int wn = w & 3;       // 0..3
  const int lr = lane & 15;
  const int hi = lane >> 4;

  // XCD-aware bijective swizzle (gridDim.x % 8 == 0 by construction)
  const int nwg = gridDim.x;
  const int cpx = nwg >> 3;
  const int bid = blockIdx.x;
  const int wg = (bid & 7) * cpx + (bid >> 3);
  const int bx = wg % NBX;
  const int by = wg / NBX;
  const int row0 = by * 256;
  const int col0 = bx * BN;

  const bf16* Ag = A + (size_t)row0 * K;
  const bf16* Bg = B + (size_t)col0 * K;

  // prologue: A(0),A(1); B(0) [+B(1) for NBB=3]; full drain (one-time)
#pragma unroll
  for (int p = 0; p < 4; ++p) stage_part(Ag, K, 0, Ab, p, tid);
#pragma unroll
  for (int p = 0; p < 4; ++p) stage_part(Ag, K, 1, Ab + 16384, p, tid);
#pragma unroll
  for (int p = 0; p < LB; ++p) stage_part(Bg, K, 0, Bb, p, tid);
  if constexpr (NFRAG == 2) {
#pragma unroll
    for (int p = 0; p < LB; ++p) stage_part(Bg, K, 1, Bb + BN * 64, p, tid);
  }
  asm volatile("s_waitcnt vmcnt(0)" ::: "memory");
  __builtin_amdgcn_s_barrier();

  f32x4 acc[8][NFRAG] = {};
  bf16x8 af[8][2], bfv[2][2], bf2[2];

  const int ntile = K >> 6;  // BK=64
  for (int t = 0; t < ntile; ++t) {
    const bf16* Acur = Ab + (t % 3) * 16384;
    const bf16* Bcur = Bb + (t % NBB) * (BN * 64);
    bf16* Adst = Ab + ((t + 2) % 3) * 16384;
    bf16* Bdst = Bb + ((t + AB) % NBB) * (BN * 64);
    const bool sA = (t + 2 < ntile);
    const bool sB = (t + AB < ntile);

    // ---- P1: DS A(m0-3) + B(n0,n1); stage B(t+AB); 16 MFMA ----
#pragma unroll
    for (int m = 0; m < 4; ++m)
#pragma unroll
      for (int ks = 0; ks < 2; ++ks)
        af[m][ks] = rd_swz(Acur, wm * 128 + m * 16 + lr, ks, hi);
#pragma unroll
    for (int n = 0; n < 2; ++n)
#pragma unroll
      for (int ks = 0; ks < 2; ++ks)
        bfv[n][ks] = rd_swz(Bcur, wn * WN + n * 16 + lr, ks, hi);
    if (sB) {
#pragma unroll
      for (int p = 0; p < LB; ++p) stage_part(Bg, K, t + AB, Bdst, p, tid);
    }
    PHASE_SYNC_PRE();
    __builtin_amdgcn_s_setprio(1);
#pragma unroll
    for (int ks = 0; ks < 2; ++ks)
#pragma unroll
      for (int m = 0; m < 4; ++m)
#pragma unroll
        for (int n = 0; n < 2; ++n)
          acc[m][n] = __builtin_amdgcn_mfma_f32_16x16x32_bf16(
              af[m][ks], bfv[n][ks], acc[m][n], 0, 0, 0);
    __builtin_amdgcn_s_setprio(0);
    PHASE_END();

    // ---- P2: DS A(m4-7); stage A(t+2); 16 MFMA ----
#pragma unroll
    for (int m = 0; m < 4; ++m)
#pragma unroll
      for (int ks = 0; ks < 2; ++ks)
        af[4 + m][ks] = rd_swz(Acur, wm * 128 + 64 + m * 16 + lr, ks, hi);
    if constexpr (NFRAG == 2) {
      if (sA) {
#pragma unroll
        for (int p = 0; p < 4; ++p) stage_part(Ag, K, t + 2, Adst, p, tid);
        asm volatile("s_waitcnt vmcnt(6)" ::: "memory");  // retire tile t+1 loads
      } else {
        asm volatile("s_waitcnt vmcnt(0)" ::: "memory");
      }
      PHASE_SYNC_PRE();
      __builtin_amdgcn_s_setprio(1);
#pragma unroll
      for (int ks = 0; ks < 2; ++ks)
#pragma unroll
        for (int m = 0; m < 4; ++m)
#pragma unroll
          for (int n = 0; n < 2; ++n)
            acc[4 + m][n] = __builtin_amdgcn_mfma_f32_16x16x32_bf16(
                af[4 + m][ks], bfv[n][ks], acc[4 + m][n], 0, 0, 0);
      __builtin_amdgcn_s_setprio(0);
      PHASE_END();
    } else {
      if (sA) {
        stage_part(Ag, K, t + 2, Adst, 0, tid);
        stage_part(Ag, K, t + 2, Adst, 1, tid);
      }
      PHASE_SYNC_PRE();
      __builtin_amdgcn_s_setprio(1);
#pragma unroll
      for (int ks = 0; ks < 2; ++ks)
#pragma unroll
        for (int m = 0; m < 4; ++m)
#pragma unroll
          for (int n = 0; n < 2; ++n)
            acc[4 + m][n] = __builtin_amdgcn_mfma_f32_16x16x32_bf16(
                af[4 + m][ks], bfv[n][ks], acc[4 + m][n], 0, 0, 0);
      __builtin_amdgcn_s_setprio(0);
      PHASE_END();

      // ---- P3 (BN=192 only): DS B(n2); finish A(t+2); vmcnt(4); 16 MFMA ----
#pragma unroll
      for (int ks = 0; ks < 2; ++ks)
        bf2[ks] = rd_swz(Bcur, wn * WN + 32 + lr, ks, hi);
      if (sA) {
        stage_part(Ag, K, t + 2, Adst, 2, tid);
        stage_part(Ag, K, t + 2, Adst, 3, tid);
        asm volatile("s_waitcnt vmcnt(4)" ::: "memory");  // retire A(t+1)+B(t+1)
      } else {
        asm volatile("s_waitcnt vmcnt(0)" ::: "memory");
      }
      PHASE_SYNC_PRE();
      __builtin_amdgcn_s_setprio(1);
#pragma unroll
      for (int ks = 0; ks < 2; ++ks)
#pragma unroll
        for (int m = 0; m < 8; ++m)
          acc[m][NFRAG - 1] = __builtin_amdgcn_mfma_f32_16x16x32_bf16(
              af[m][ks], bf2[ks], acc[m][NFRAG - 1], 0, 0, 0);
      __builtin_amdgcn_s_setprio(0);
      PHASE_END();
    }
  }

  // epilogue: C write (C/D layout: col=lane&15, row=(lane>>4)*4+j)
#pragma unroll
  for (int mi = 0; mi < 8; ++mi)
#pragma unroll
    for (int ni = 0; ni < NFRAG; ++ni)
#pragma unroll
      for (int j = 0; j < 4; ++j) {
        const int r = row0 + wm * 128 + mi * 16 + hi * 4 + j;
        const int cc = col0 + wn * WN + ni * 16 + lr;
        store_c(acc[mi][ni][j], &C[(size_t)r * N + cc]);
      }
}

// ---------------- fused RoPE-scatter + V-transpose (one dispatch) ------------
__global__ __launch_bounds__(256) void rope_vtrans(const bf16* __restrict__ qkv,
                                                   const float* __restrict__ cs,
                                                   const float* __restrict__ sn,
                                                   bf16* __restrict__ Q,
                                                   bf16* __restrict__ Kd,
                                                   bf16* __restrict__ Vt) {
  __shared__ bf16 tile[64 * 136];  // used by vtrans blocks only
  const int bid = blockIdx.x;
  if (bid < 4096) {
    // ---- RoPE + scatter; Q pre-scaled by QSCALE_LOG2E ----
    const int tok = bid;
    const int b = tok >> 11;
    const int s = tok & 2047;
    const bf16* row = qkv + (size_t)tok * 3072;
    for (int idx = threadIdx.x; idx < 1280; idx += blockDim.x) {
      const int head = idx >> 6;  // 0..19 (q:0-15, k:16-19)
      const int j = idx & 63;
      float x1 = __bfloat162float(row[head * 128 + j]);
      float x2 = __bfloat162float(row[head * 128 + j + 64]);
      const float c1 = cs[s * 128 + j];
      const float c2 = cs[s * 128 + j + 64];
      const float s1 = sn[s * 128 + j];
      const float s2 = sn[s * 128 + j + 64];
      float y1 = x1 * c1 - x2 * s1;
      float y2 = x2 * c2 + x1 * s2;
      bf16* dst;
      if (head < 16) {
        y1 *= QSCALE_LOG2E;
        y2 *= QSCALE_LOG2E;
        dst = Q + ((size_t)(b * 16 + head) * 2048 + s) * 128;
      } else {
        dst = Kd + ((size_t)(b * 4 + head - 16) * 2048 + s) * 128;
      }
      dst[j] = __float2bfloat16(y1);
      dst[j + 64] = __float2bfloat16(y2);
    }
  } else {
    // ---- V transpose: qkv v-heads -> Vt [b][kv][128][2048] ----
    const int vb = bid - 4096;     // 0..255
    const int stile = vb & 31;
    const int hv = (vb >> 5) & 3;
    const int b = vb >> 7;
    const int tid = threadIdx.x;
    const int tok0 = stile * 64;
    const bf16* src = qkv + (size_t)(b * 2048 + tok0) * 3072 + 2560 + hv * 128;
#pragma unroll
    for (int i = 0; i < 4; ++i) {
      const int c = tid + i * 256;
      const int r = c >> 4;
      const int off = (c & 15) * 8;
      uint4 d = *reinterpret_cast<const uint4*>(src + (size_t)r * 3072 + off);
      *reinterpret_cast<uint4*>(&tile[r * 136 + off]) = d;
    }
    __syncthreads();
    bf16* dst = Vt + ((size_t)(b * 4 + hv) * 128) * 2048 + tok0;
#pragma unroll
    for (int i = 0; i < 4; ++i) {
      const int o = tid + i * 256;
      const int d = o >> 3;
      const int s0 = (o & 7) * 8;
      bf16 vals[8];
#pragma unroll
      for (int j = 0; j < 8; ++j) vals[j] = tile[(s0 + j) * 136 + d];
      *reinterpret_cast<uint4*>(dst + (size_t)d * 2048 + s0) =
          *reinterpret_cast<const uint4*>(vals);
    }
  }
}

// ---------------- causal GQA flash attention (round-7 verified, 61 us) -------
// 4 waves/block, each wave owns 32 q-rows (QBLK=128), KV tile = 64.
// 32x32x16 MFMA, swapped QK^T, in-register softmax, cvt_pk+permlane PV.
// NOTE: requires the 104-VGPR / 2-blocks-per-CU operating point; capping
// registers via launch_bounds occupancy args causes catastrophic spill
// (rounds 10 & 12 post-mortems).
__device__ __forceinline__ void stage_k(const bf16* __restrict__ Kb, int k0,
                                        bf16* dst, int w, int lane) {
#pragma unroll
  for (int i = 0; i < 4; ++i) {
    const int L16 = i * 256 + w * 64 + lane;  // chunk 0..1023
    const int row = L16 >> 4;                 // 256B rows
    const int colb = (L16 & 15) * 16;
    const int src = colb ^ ((row & 7) << 4);
    gload_lds16(Kb + (size_t)(k0 + row) * 128 + (src >> 1),
                (char*)dst + (i * 256 + w * 64) * 16);
  }
}

__device__ __forceinline__ void stage_v(const bf16* __restrict__ Vtb, int k0,
                                        bf16* dst, int w, int lane) {
#pragma unroll
  for (int i = 0; i < 4; ++i) {
    const int L16 = i * 256 + w * 64 + lane;  // chunk 0..1023
    const int row = L16 >> 3;                 // 128B rows (d = 0..127)
    const int colb = (L16 & 7) * 16;
    const int src = colb ^ ((row & 7) << 4);
    gload_lds16(Vtb + (size_t)row * 2048 + k0 + (src >> 1),
                (char*)dst + (i * 256 + w * 64) * 16);
  }
}

__device__ __forceinline__ bf16x8 lds_read_swz(const bf16* base, int row,
                                               int colElem, int rowBytes) {
  const int byte = row * rowBytes + (((colElem * 2) ^ ((row & 7) << 4)));
  return *reinterpret_cast<const bf16x8*>((const char*)base + byte);
}

__global__ __launch_bounds__(256, 2) void attn_fwd(const bf16* __restrict__ Qg,
                                                   const bf16* __restrict__ Kg,
                                                   const bf16* __restrict__ Vtg,
                                                   bf16* __restrict__ Og) {
  __shared__ bf16 Ks[2][64 * 128];  // 32 KB (swizzled)
  __shared__ bf16 Vs[2][128 * 64];  // 32 KB (swizzled, [d][k])

  const int tid = threadIdx.x;
  const int lane = tid & 63;
  const int w = tid >> 6;
  // block remap: blocks i and i+256 have complementary lengths (qt sums to 15)
  const int bid = blockIdx.x;  // 0..511
  int qt, bh;
  if (bid < 256) { qt = bid & 15; bh = bid >> 4; }
  else           { qt = 15 - (bid & 15); bh = 16 + ((bid - 256) >> 4); }
  const int b = bh >> 4;
  const int h = bh & 15;
  const int kvh = h >> 2;
  const int q31 = lane & 31;
  const int hw = lane >> 5;

  const bf16* Qb = Qg + ((size_t)(b * 16 + h) * 2048) * 128;
  const bf16* Kb = Kg + ((size_t)(b * 4 + kvh) * 2048) * 128;
  const bf16* Vtb = Vtg + ((size_t)(b * 4 + kvh) * 128) * 2048;

  const int qw = qt * 128 + w * 32;  // this wave's first q-row

  // hoist Q as B-operand fragments: col=q=lane&31, k=d = db*16 + 8*hw + j
  bf16x8 qf[8];
#pragma unroll
  for (int db = 0; db < 8; ++db)
    qf[db] = *reinterpret_cast<const bf16x8*>(Qb + (size_t)(qw + q31) * 128 +
                                              db * 16 + hw * 8);

  f32x16 acc[4] = {};   // O: row=q spread over regs, col=d=lane&31
  float mrow = -1e30f;  // per-lane q = qw + q31 (log2 domain)
  float lsum = 0.f;

  const int nt = 2 * qt + 2;

  // prologue: stage tile 0 (8 gload_lds per wave in flight)
  stage_k(Kb, 0, &Ks[0][0], w, lane);
  stage_v(Vtb, 0, &Vs[0][0], w, lane);

  for (int t = 0; t < nt; ++t) {
    const int cur = t & 1;
    if (t + 1 < nt) {
      stage_k(Kb, (t + 1) * 64, &Ks[cur ^ 1][0], w, lane);
      stage_v(Vtb, (t + 1) * 64, &Vs[cur ^ 1][0], w, lane);
      asm volatile("s_waitcnt vmcnt(8)" ::: "memory");  // tile t retired
    } else {
      asm volatile("s_waitcnt vmcnt(0)" ::: "memory");
    }
    __builtin_amdgcn_s_barrier();  // A: everyone's tile-t writes visible
    __builtin_amdgcn_sched_barrier(0);

    const int k0 = t * 64;
    const bool active = (k0 <= qw + 31);  // skip fully-masked tiles
    if (active) {
      const bf16* Kt = &Ks[cur][0];
      const bf16* Vtl = &Vs[cur][0];

      // S^T = K Q : per kb32, D col=q=lane&31, row=k=(r&3)+8*(r>>2)+4*hw
      f32x16 sacc[2] = {};
#pragma unroll
      for (int kb = 0; kb < 2; ++kb)
#pragma unroll
        for (int db = 0; db < 8; ++db) {
          bf16x8 kf = lds_read_swz(Kt, kb * 32 + q31, db * 16 + hw * 8, 256);
          sacc[kb] = __builtin_amdgcn_mfma_f32_32x32x16_bf16(kf, qf[db],
                                                             sacc[kb], 0, 0, 0);
        }

      float p[2][16];
#pragma unroll
      for (int kb = 0; kb < 2; ++kb)
#pragma unroll
        for (int r = 0; r < 16; ++r) p[kb][r] = sacc[kb][r];

      if (k0 + 63 > qw) {  // mask only on diagonal-crossing tiles
        const int qg = qw + q31;
#pragma unroll
        for (int kb = 0; kb < 2; ++kb)
#pragma unroll
          for (int r = 0; r < 16; ++r) {
            const int k = k0 + kb * 32 + (r & 3) + 8 * (r >> 2) + 4 * hw;
            if (k > qg) p[kb][r] = -1e30f;
          }
      }

      // row max: in-lane over 32 values + cross-half exchange
      float mt = p[0][0];
#pragma unroll
      for (int r = 1; r < 16; ++r) mt = fmaxf(mt, p[0][r]);
#pragma unroll
      for (int r = 0; r < 16; ++r) mt = fmaxf(mt, p[1][r]);
      mt = fmaxf(mt, __shfl_xor(mt, 32));

      // defer-max: rescale only when the max grew past threshold (log2 units)
      if (__any(mt > mrow + 11.5f)) {
        const float mnew = fmaxf(mrow, mt);
        const float alpha = fast_exp2(mrow - mnew);
        mrow = mnew;
        lsum *= alpha;
        float areg[16];
#pragma unroll
        for (int r = 0; r < 16; ++r) {
          const int qloc = (r & 3) + 8 * (r >> 2) + 4 * hw;
          areg[r] = __shfl(alpha, qloc + (lane & 32));
        }
#pragma unroll
        for (int db = 0; db < 4; ++db)
#pragma unroll
          for (int r = 0; r < 16; ++r) acc[db][r] *= areg[r];
      }

      // P = 2^(S - m), row sum in-lane + cross-half
      float rs = 0.f;
#pragma unroll
      for (int kb = 0; kb < 2; ++kb)
#pragma unroll
        for (int r = 0; r < 16; ++r) {
          const float pe = fast_exp2(p[kb][r] - mrow);
          p[kb][r] = pe;
          rs += pe;
        }
      rs += __shfl_xor(rs, 32);
      lsum += rs;

      // pack P to bf16 pairs: pk[kb][i] = (p[2i], p[2i+1])
      unsigned int pk[2][8];
#pragma unroll
      for (int kb = 0; kb < 2; ++kb)
#pragma unroll
        for (int i = 0; i < 8; ++i)
          asm("v_cvt_pk_bf16_f32 %0, %1, %2"
              : "=v"(pk[kb][i])
              : "v"(p[kb][2 * i]), "v"(p[kb][2 * i + 1]));

      // PV: A-frag kb16 via 2 permlane32_swap; B = V^T rows (col=d=lane&31)
#pragma unroll
      for (int kb16 = 0; kb16 < 4; ++kb16) {
        const int kb = kb16 >> 1;
        const int j0 = (kb16 & 1) * 4;
        unsigned int a0 = pk[kb][j0 + 0], b0 = pk[kb][j0 + 2];
        unsigned int a1 = pk[kb][j0 + 1], b1 = pk[kb][j0 + 3];
        asm volatile("v_permlane32_swap_b32 %0, %1" : "+v"(a0), "+v"(b0));
        asm volatile("v_permlane32_swap_b32 %0, %1" : "+v"(a1), "+v"(b1));
        u32x4 afu;
        afu.x = a0; afu.y = a1; afu.z = b0; afu.w = b1;
        bf16x8 pa;
        __builtin_memcpy(&pa, &afu, 16);
#pragma unroll
        for (int db = 0; db < 4; ++db) {
          bf16x8 vf = lds_read_swz(Vtl, db * 32 + q31, kb16 * 16 + hw * 8, 128);
          acc[db] = __builtin_amdgcn_mfma_f32_32x32x16_bf16(pa, vf,
                                                            acc[db], 0, 0, 0);
        }
      }
    }

    __builtin_amdgcn_sched_barrier(0);
    __builtin_amdgcn_s_barrier();  // B: all reads of tile t done
  }

  // epilogue: translate per-q lsum to per-reg, normalize, store
  const float inv = 1.0f / lsum;
  float invq[16];
#pragma unroll
  for (int r = 0; r < 16; ++r) {
    const int qloc = (r & 3) + 8 * (r >> 2) + 4 * hw;
    invq[r] = __shfl(inv, qloc + (lane & 32));
  }
#pragma unroll
  for (int db = 0; db < 4; ++db)
#pragma unroll
    for (int r = 0; r < 16; ++r) {
      const int qg = qw + (r & 3) + 8 * (r >> 2) + 4 * hw;
      const int dg = db * 32 + q31;
      Og[((size_t)(b * 2048 + qg)) * 2048 + h * 128 + dg] =
          __float2bfloat16(acc[db][r] * invq[r]);
    }
}

// ---------------- launcher ----------------------------------------------------
extern "C" void kernel_launch(void* const* d_in, const int* in_sizes, int n_in,
                              void* d_out, int out_size, void* d_ws,
                              size_t ws_size, hipStream_t stream) {
  const float* hidden = (const float*)d_in[0];
  const float* cs = (const float*)d_in[1];
  const float* sn = (const float*)d_in[2];
  const float* wqkv = (const float*)d_in[3];
  const float* wo = (const float*)d_in[4];
  float* out = (float*)d_out;

  bf16* p = (bf16*)d_ws;
  bf16* hid_b = p;   p += 8388608;   // reused later as attn out
  bf16* wqkv_b = p;  p += 6291456;
  bf16* wo_b = p;    p += 4194304;
  bf16* qkv = p;     p += 12582912;  // [4096][3072] pre-RoPE
  bf16* Qs = p;      p += 8388608;   // [2][16][2048][128] (pre-scaled)
  bf16* Ksc = p;     p += 2097152;   // [2][4][2048][128]
  bf16* Vt = p;      p += 2097152;   // [2][4][128][2048]  (V transposed)

  // allow 144 KiB dynamic LDS for the deep-pipeline GEMMs (idempotent)
  (void)hipFuncSetAttribute((const void*)gemm_dp<192, bf16>,
                            hipFuncAttributeMaxDynamicSharedMemorySize, 147456);
  (void)hipFuncSetAttribute((const void*)gemm_dp<128, float>,
                            hipFuncAttributeMaxDynamicSharedMemorySize, 147456);

  cast3<<<2048, 256, 0, stream>>>(hidden, wqkv, wo, hid_b, wqkv_b, wo_b);

  // QKV: M=4096, N=3072, K=2048; BN=192 -> 16x16 = 256 blocks (full fill)
  gemm_dp<192, bf16><<<256, 512, 147456, stream>>>(hid_b, wqkv_b, qkv,
                                                   4096, 3072, 2048, 16);
  rope_vtrans<<<4352, 256, 0, stream>>>(qkv, cs, sn, Qs, Ksc, Vt);

  bf16* aout = hid_b;
  attn_fwd<<<512, 256, 0, stream>>>(Qs, Ksc, Vt, aout);

  // out-proj: M=4096, N=2048, K=2048; BN=128 -> 16x16 = 256 blocks (full fill)
  gemm_dp<128, float><<<256, 512, 147456, stream>>>(aout, wo_b, out,
                                                    4096, 2048, 2048, 16);
}

// Round 15
// 171.544 us; speedup vs baseline: 1.0319x; 1.0319x over previous
//
#include <hip/hip_runtime.h>
#include <hip/hip_bf16.h>
#include <stdint.h>

// Problem constants: B=2, S=2048, H=2048, HEAD_DIM=128, NUM_HEADS=16, NUM_KV=4
typedef __hip_bfloat16 bf16;
typedef __attribute__((ext_vector_type(8))) __bf16 bf16x8;
typedef __attribute__((ext_vector_type(4))) float f32x4;
typedef __attribute__((ext_vector_type(16))) float f32x16;
typedef __attribute__((ext_vector_type(4))) unsigned int u32x4;

// scale (1/sqrt(128)) * log2(e): folded into Q at RoPE time -> scores in log2 domain
#define QSCALE_LOG2E (0.08838834764831845f * 1.4426950408889634f)

__device__ __forceinline__ float fast_exp2(float x) {
#if __has_builtin(__builtin_amdgcn_exp2f)
  return __builtin_amdgcn_exp2f(x);
#else
  return exp2f(x);
#endif
}

// ---------------- async global->LDS (wave-uniform LDS base + lane*16) -------
__device__ __forceinline__ void gload_lds16(const void* g, void* l) {
  __builtin_amdgcn_global_load_lds(
      (__attribute__((address_space(1))) void*)(uintptr_t)g,
      (__attribute__((address_space(3))) void*)(uint32_t)(uintptr_t)l,
      16, 0, 0);
}

// ---------------- fused fp32 -> bf16 cast (hidden + w_qkv + w_o) -------------
__global__ void cast3(const float* __restrict__ h, const float* __restrict__ wq,
                      const float* __restrict__ wo, bf16* __restrict__ oh,
                      bf16* __restrict__ owq, bf16* __restrict__ owo) {
  const int total = 4718592;  // float4 chunks: 2097152 + 1572864 + 1048576
  const int stride = gridDim.x * blockDim.x;
  for (int c = blockIdx.x * blockDim.x + threadIdx.x; c < total; c += stride) {
    const float* src;
    bf16* dst;
    int i;
    if (c < 2097152) { src = h; dst = oh; i = c; }
    else if (c < 3670016) { src = wq; dst = owq; i = c - 2097152; }
    else { src = wo; dst = owo; i = c - 3670016; }
    float4 v = reinterpret_cast<const float4*>(src)[i];
    bf16 tmp[4];
    tmp[0] = __float2bfloat16(v.x);
    tmp[1] = __float2bfloat16(v.y);
    tmp[2] = __float2bfloat16(v.z);
    tmp[3] = __float2bfloat16(v.w);
    reinterpret_cast<uint2*>(dst)[i] = *reinterpret_cast<uint2*>(tmp);
  }
}

// ---------------- 256xBN 8-phase GEMM (C = A * B^T) — round-9 verified -------
__device__ __forceinline__ void store_c(float v, bf16* p) { *p = __float2bfloat16(v); }
__device__ __forceinline__ void store_c(float v, float* p) { *p = v; }

__device__ __forceinline__ bf16x8 rd_swz(const bf16* base, int row, int ks, int hi) {
  const int byte = row * 128 + ((ks * 64 + hi * 16) ^ ((row & 7) << 4));
  return *reinterpret_cast<const bf16x8*>((const char*)base + byte);
}

// stage granules [part*512, part*512+512) of a tile (rows x 64 cols) for K-step kt
__device__ __forceinline__ void stage_part(const bf16* __restrict__ g, int K,
                                           int kt, bf16* ldsBase, int part,
                                           int tid) {
  const int ga = part * 512 + tid;  // granule index within tile
  const int r = ga >> 3;            // row
  const int gl = ga & 7;            // 16B granule within row
  const int col = kt * 64 + ((gl ^ (r & 7)) << 3);
  gload_lds16(g + (size_t)r * K + col, (char*)ldsBase + ga * 16);
}

#define DS_A(QR)                                                              \
  _Pragma("unroll") for (int m = 0; m < 4; ++m)                               \
  _Pragma("unroll") for (int ks = 0; ks < 2; ++ks)                            \
      af[m][ks] = rd_swz(Acur, wm * 128 + (QR) * 64 + m * 16 + lr, ks, hi);

#define DS_B0()                                                               \
  _Pragma("unroll") for (int n = 0; n < NQ0; ++n)                             \
  _Pragma("unroll") for (int ks = 0; ks < 2; ++ks)                            \
      bf0[n][ks] = rd_swz(Bcur, wn * WN + n * 16 + lr, ks, hi);

#define DS_B1()                                                               \
  _Pragma("unroll") for (int n = 0; n < NQ1; ++n)                             \
  _Pragma("unroll") for (int ks = 0; ks < 2; ++ks)                            \
      bf1[n][ks] = rd_swz(Bcur, wn * WN + (NQ0 + n) * 16 + lr, ks, hi);

#define MFMA_Q0(QR)                                                           \
  __builtin_amdgcn_s_setprio(1);                                             \
  _Pragma("unroll") for (int ks = 0; ks < 2; ++ks)                            \
  _Pragma("unroll") for (int m = 0; m < 4; ++m)                               \
  _Pragma("unroll") for (int n = 0; n < NQ0; ++n)                             \
      acc[(QR) * 4 + m][n] = __builtin_amdgcn_mfma_f32_16x16x32_bf16(         \
          af[m][ks], bf0[n][ks], acc[(QR) * 4 + m][n], 0, 0, 0);              \
  __builtin_amdgcn_s_setprio(0);

#define MFMA_Q1(QR)                                                           \
  __builtin_amdgcn_s_setprio(1);                                             \
  _Pragma("unroll") for (int ks = 0; ks < 2; ++ks)                            \
  _Pragma("unroll") for (int m = 0; m < 4; ++m)                               \
  _Pragma("unroll") for (int n = 0; n < NQ1; ++n)                             \
      acc[(QR) * 4 + m][NQ0 + n] = __builtin_amdgcn_mfma_f32_16x16x32_bf16(   \
          af[m][ks], bf1[n][ks], acc[(QR) * 4 + m][NQ0 + n], 0, 0, 0);        \
  __builtin_amdgcn_s_setprio(0);

#define PHASE_SYNC_PRE()                                \
  __builtin_amdgcn_s_barrier();                         \
  asm volatile("s_waitcnt lgkmcnt(0)" ::: "memory");    \
  __builtin_amdgcn_sched_barrier(0);

#define PHASE_END() __builtin_amdgcn_s_barrier();

#define VMCNT_LB()                                                            \
  if constexpr (LB == 2) asm volatile("s_waitcnt vmcnt(2)" ::: "memory");     \
  else if constexpr (LB == 3) asm volatile("s_waitcnt vmcnt(3)" ::: "memory");\
  else asm volatile("s_waitcnt vmcnt(4)" ::: "memory");

template <int BN, typename OutT>
__global__ __launch_bounds__(512, 2) void gemm256(const bf16* __restrict__ A,
                                                  const bf16* __restrict__ B,
                                                  OutT* __restrict__ C,
                                                  int M, int N, int K, int NBX) {
  constexpr int NFRAG = BN / 64;       // n-frags per wave (wave tile 128 x BN/4)
  constexpr int NQ0 = (NFRAG + 1) / 2; // frags in first column-half
  constexpr int NQ1 = NFRAG - NQ0;
  constexpr int WN = BN / 4;
  constexpr int LB = BN / 64;          // B loads/thread per K-tile
  constexpr int LB0 = (LB + 1) / 2;    // staged at p3/p7
  constexpr int LB1 = LB - LB0;        // staged at p4/p8

  extern __shared__ bf16 sm[];
  bf16* A0 = sm;                    // [256][64]
  bf16* A1 = sm + 16384;
  bf16* B0 = sm + 32768;            // [BN][64]
  bf16* B1 = B0 + BN * 64;

  const int tid = threadIdx.x;
  const int lane = tid & 63;
  const int w = tid >> 6;
  const int wm = w >> 2;      // 0..1
  const int wn = w & 3;       // 0..3
  const int lr = lane & 15;
  const int hi = lane >> 4;

  // XCD-aware bijective swizzle (gridDim.x % 8 == 0 by construction)
  const int nwg = gridDim.x;
  const int cpx = nwg >> 3;
  const int bid = blockIdx.x;
  const int wg = (bid & 7) * cpx + (bid >> 3);
  const int bx = wg % NBX;
  const int by = wg / NBX;
  const int row0 = by * 256;
  const int col0 = bx * BN;

  const bf16* Ag = A + (size_t)row0 * K;
  const bf16* Bg = B + (size_t)col0 * K;

  // prologue: A(t0), B(t0), B(t1); retire t0 -> vmcnt(LB)
#pragma unroll
  for (int p = 0; p < 4; ++p) stage_part(Ag, K, 0, A0, p, tid);
#pragma unroll
  for (int p = 0; p < LB; ++p) stage_part(Bg, K, 0, B0, p, tid);
#pragma unroll
  for (int p = 0; p < LB; ++p) stage_part(Bg, K, 1, B1, p, tid);
  VMCNT_LB();
  __builtin_amdgcn_s_barrier();

  f32x4 acc[8][NFRAG] = {};
  bf16x8 af[4][2], bf0[NQ0][2], bf1[NQ1 ? NQ1 : 1][2];

  const int iters = K >> 7;  // 2 K-tiles per iteration
  for (int i = 0; i < iters; ++i) {
    const bool g2 = (i + 1 < iters);
    const int t1 = 2 * i + 1, t2 = 2 * i + 2, t3 = 2 * i + 3;
    {  // ---- phases 1-4: compute K-tile 2i from buf0 ----
      const bf16* Acur = A0;
      const bf16* Bcur = B0;
      // p1
      DS_A(0); DS_B0();
      stage_part(Ag, K, t1, A1, 0, tid);
      stage_part(Ag, K, t1, A1, 1, tid);
      PHASE_SYNC_PRE(); MFMA_Q0(0); PHASE_END();
      // p2
      DS_B1();
      stage_part(Ag, K, t1, A1, 2, tid);
      stage_part(Ag, K, t1, A1, 3, tid);
      PHASE_SYNC_PRE(); MFMA_Q1(0); PHASE_END();
      // p3 (B-buf0 reads finished at p2's barrier)
      DS_A(1);
      if (g2) {
#pragma unroll
        for (int p = 0; p < LB0; ++p) stage_part(Bg, K, t2, B0, p, tid);
      }
      PHASE_SYNC_PRE(); MFMA_Q0(1); PHASE_END();
      // p4
      if (g2) {
#pragma unroll
        for (int p = 0; p < LB1; ++p) stage_part(Bg, K, t2, B0, LB0 + p, tid);
        VMCNT_LB();  // A(t1) landed
      } else {
        asm volatile("s_waitcnt vmcnt(0)" ::: "memory");
      }
      PHASE_SYNC_PRE(); MFMA_Q1(1); PHASE_END();
    }
    {  // ---- phases 5-8: compute K-tile 2i+1 from buf1 ----
      const bf16* Acur = A1;
      const bf16* Bcur = B1;
      // p5 (A-buf0 reads finished at p3's barrier)
      DS_A(0); DS_B0();
      if (g2) {
        stage_part(Ag, K, t2, A0, 0, tid);
        stage_part(Ag, K, t2, A0, 1, tid);
      }
      PHASE_SYNC_PRE(); MFMA_Q0(0); PHASE_END();
      // p6
      DS_B1();
      if (g2) {
        stage_part(Ag, K, t2, A0, 2, tid);
        stage_part(Ag, K, t2, A0, 3, tid);
      }
      PHASE_SYNC_PRE(); MFMA_Q1(0); PHASE_END();
      // p7 (B-buf1 reads finished at p6's barrier)
      DS_A(1);
      if (g2) {
#pragma unroll
        for (int p = 0; p < LB0; ++p) stage_part(Bg, K, t3, B1, p, tid);
      }
      PHASE_SYNC_PRE(); MFMA_Q0(1); PHASE_END();
      // p8
      if (g2) {
#pragma unroll
        for (int p = 0; p < LB1; ++p) stage_part(Bg, K, t3, B1, LB0 + p, tid);
        VMCNT_LB();  // B(t2)+A(t2) landed
      } else {
        asm volatile("s_waitcnt vmcnt(0)" ::: "memory");
      }
      PHASE_SYNC_PRE(); MFMA_Q1(1); PHASE_END();
    }
  }

  // epilogue: C write (C/D layout: col=lane&15, row=(lane>>4)*4+j)
#pragma unroll
  for (int mi = 0; mi < 8; ++mi)
#pragma unroll
    for (int ni = 0; ni < NFRAG; ++ni)
#pragma unroll
      for (int j = 0; j < 4; ++j) {
        const int r = row0 + wm * 128 + mi * 16 + hi * 4 + j;
        const int cc = col0 + wn * WN + ni * 16 + lr;
        store_c(acc[mi][ni][j], &C[(size_t)r * N + cc]);
      }
}

// ---------------- fused RoPE-scatter + V-transpose (one dispatch) ------------
// Vt is stored K-GROUPED: per (b,kv), 16B chunk index (kg, d) = kg*128 + d
// holds V^T[d][8kg .. 8kg+7]  (kg = k>>3). This makes the attention V-tile
// ds_read conflict-free (lanes = consecutive d = consecutive 16B chunks) and
// the gload_lds staging fully coalesced.
__global__ __launch_bounds__(256) void rope_vtrans(const bf16* __restrict__ qkv,
                                                   const float* __restrict__ cs,
                                                   const float* __restrict__ sn,
                                                   bf16* __restrict__ Q,
                                                   bf16* __restrict__ Kd,
                                                   bf16* __restrict__ Vt) {
  __shared__ bf16 tile[64 * 136];  // used by vtrans blocks only
  const int bid = blockIdx.x;
  if (bid < 4096) {
    // ---- RoPE + scatter; Q pre-scaled by QSCALE_LOG2E ----
    const int tok = bid;
    const int b = tok >> 11;
    const int s = tok & 2047;
    const bf16* row = qkv + (size_t)tok * 3072;
    for (int idx = threadIdx.x; idx < 1280; idx += blockDim.x) {
      const int head = idx >> 6;  // 0..19 (q:0-15, k:16-19)
      const int j = idx & 63;
      float x1 = __bfloat162float(row[head * 128 + j]);
      float x2 = __bfloat162float(row[head * 128 + j + 64]);
      const float c1 = cs[s * 128 + j];
      const float c2 = cs[s * 128 + j + 64];
      const float s1 = sn[s * 128 + j];
      const float s2 = sn[s * 128 + j + 64];
      float y1 = x1 * c1 - x2 * s1;
      float y2 = x2 * c2 + x1 * s2;
      bf16* dst;
      if (head < 16) {
        y1 *= QSCALE_LOG2E;
        y2 *= QSCALE_LOG2E;
        dst = Q + ((size_t)(b * 16 + head) * 2048 + s) * 128;
      } else {
        dst = Kd + ((size_t)(b * 4 + head - 16) * 2048 + s) * 128;
      }
      dst[j] = __float2bfloat16(y1);
      dst[j + 64] = __float2bfloat16(y2);
    }
  } else {
    // ---- V transpose into k-grouped layout ----
    const int vb = bid - 4096;     // 0..255
    const int stile = vb & 31;
    const int hv = (vb >> 5) & 3;
    const int b = vb >> 7;
    const int tid = threadIdx.x;
    const int tok0 = stile * 64;
    const bf16* src = qkv + (size_t)(b * 2048 + tok0) * 3072 + 2560 + hv * 128;
#pragma unroll
    for (int i = 0; i < 4; ++i) {
      const int c = tid + i * 256;
      const int r = c >> 4;          // token within tile
      const int off = (c & 15) * 8;  // d offset
      uint4 d = *reinterpret_cast<const uint4*>(src + (size_t)r * 3072 + off);
      *reinterpret_cast<uint4*>(&tile[r * 136 + off]) = d;
    }
    __syncthreads();
    bf16* dst8 = Vt + ((size_t)(b * 4 + hv) * 128) * 2048;  // k-grouped base
#pragma unroll
    for (int i = 0; i < 4; ++i) {
      const int o = tid + i * 256;  // 1024 chunks
      const int kgl = o >> 7;       // local k-group 0..7
      const int d = o & 127;
      bf16 vals[8];
#pragma unroll
      for (int j = 0; j < 8; ++j) vals[j] = tile[(kgl * 8 + j) * 136 + d];
      const size_t chunk = ((size_t)(tok0 >> 3) + kgl) * 128 + d;
      *reinterpret_cast<uint4*>(dst8 + chunk * 8) =
          *reinterpret_cast<const uint4*>(vals);
    }
  }
}

// ---------------- causal GQA flash attention (round-7 verified structure) ----
// 4 waves/block, each wave owns 32 q-rows (QBLK=128), KV tile = 64.
// 32x32x16 MFMA, swapped QK^T, in-register softmax, cvt_pk+permlane PV.
// This round: V tile in k-grouped layout -> V reads conflict-free (the K
// reads were already conflict-free; the old V layout was a structural 4-way).
// NOTE: requires the ~104-VGPR / 2-blocks-per-CU operating point; capping
// registers via launch_bounds occupancy args causes catastrophic spill
// (rounds 10 & 12 post-mortems).
__device__ __forceinline__ void stage_k(const bf16* __restrict__ Kb, int k0,
                                        bf16* dst, int w, int lane) {
#pragma unroll
  for (int i = 0; i < 4; ++i) {
    const int L16 = i * 256 + w * 64 + lane;  // chunk 0..1023
    const int row = L16 >> 4;                 // 256B rows
    const int colb = (L16 & 15) * 16;
    const int src = colb ^ ((row & 7) << 4);
    gload_lds16(Kb + (size_t)(k0 + row) * 128 + (src >> 1),
                (char*)dst + (i * 256 + w * 64) * 16);
  }
}

// stage V tile (k-grouped): LDS chunk (kgl, d) <- global chunk (k0/8+kgl, d)
__device__ __forceinline__ void stage_v(const bf16* __restrict__ Vt8b, int k0,
                                        bf16* dst, int w, int lane) {
#pragma unroll
  for (int i = 0; i < 4; ++i) {
    const int ga = i * 256 + w * 64 + lane;  // chunk 0..1023
    const int kgl = ga >> 7;                 // 0..7
    const int d = ga & 127;
    const size_t chunk = ((size_t)(k0 >> 3) + kgl) * 128 + d;
    gload_lds16(Vt8b + chunk * 8, (char*)dst + ga * 16);
  }
}

__device__ __forceinline__ bf16x8 lds_read_swz(const bf16* base, int row,
                                               int colElem, int rowBytes) {
  const int byte = row * rowBytes + (((colElem * 2) ^ ((row & 7) << 4)));
  return *reinterpret_cast<const bf16x8*>((const char*)base + byte);
}

__global__ __launch_bounds__(256, 2) void attn_fwd(const bf16* __restrict__ Qg,
                                                   const bf16* __restrict__ Kg,
                                                   const bf16* __restrict__ Vtg,
                                                   bf16* __restrict__ Og) {
  __shared__ bf16 Ks[2][64 * 128];  // 32 KB (swizzled)
  __shared__ bf16 Vs[2][128 * 64];  // 32 KB (k-grouped chunks, linear)

  const int tid = threadIdx.x;
  const int lane = tid & 63;
  const int w = tid >> 6;
  // block remap: blocks i and i+256 have complementary lengths (qt sums to 15)
  const int bid = blockIdx.x;  // 0..511
  int qt, bh;
  if (bid < 256) { qt = bid & 15; bh = bid >> 4; }
  else           { qt = 15 - (bid & 15); bh = 16 + ((bid - 256) >> 4); }
  const int b = bh >> 4;
  const int h = bh & 15;
  const int kvh = h >> 2;
  const int q31 = lane & 31;
  const int hw = lane >> 5;

  const bf16* Qb = Qg + ((size_t)(b * 16 + h) * 2048) * 128;
  const bf16* Kb = Kg + ((size_t)(b * 4 + kvh) * 2048) * 128;
  const bf16* Vt8b = Vtg + ((size_t)(b * 4 + kvh) * 128) * 2048;

  const int qw = qt * 128 + w * 32;  // this wave's first q-row

  // hoist Q as B-operand fragments: col=q=lane&31, k=d = db*16 + 8*hw + j
  bf16x8 qf[8];
#pragma unroll
  for (int db = 0; db < 8; ++db)
    qf[db] = *reinterpret_cast<const bf16x8*>(Qb + (size_t)(qw + q31) * 128 +
                                              db * 16 + hw * 8);

  f32x16 acc[4] = {};   // O: row=q spread over regs, col=d=lane&31
  float mrow = -1e30f;  // per-lane q = qw + q31 (log2 domain)
  float lsum = 0.f;

  const int nt = 2 * qt + 2;

  // prologue: stage tile 0 (8 gload_lds per wave in flight)
  stage_k(Kb, 0, &Ks[0][0], w, lane);
  stage_v(Vt8b, 0, &Vs[0][0], w, lane);

  for (int t = 0; t < nt; ++t) {
    const int cur = t & 1;
    if (t + 1 < nt) {
      stage_k(Kb, (t + 1) * 64, &Ks[cur ^ 1][0], w, lane);
      stage_v(Vt8b, (t + 1) * 64, &Vs[cur ^ 1][0], w, lane);
      asm volatile("s_waitcnt vmcnt(8)" ::: "memory");  // tile t retired
    } else {
      asm volatile("s_waitcnt vmcnt(0)" ::: "memory");
    }
    __builtin_amdgcn_s_barrier();  // A: everyone's tile-t writes visible
    __builtin_amdgcn_sched_barrier(0);

    const int k0 = t * 64;
    const bool active = (k0 <= qw + 31);  // skip fully-masked tiles
    if (active) {
      const bf16* Kt = &Ks[cur][0];
      const bf16* Vtl = &Vs[cur][0];

      // S^T = K Q : per kb32, D col=q=lane&31, row=k=(r&3)+8*(r>>2)+4*hw
      f32x16 sacc[2] = {};
#pragma unroll
      for (int kb = 0; kb < 2; ++kb)
#pragma unroll
        for (int db = 0; db < 8; ++db) {
          bf16x8 kf = lds_read_swz(Kt, kb * 32 + q31, db * 16 + hw * 8, 256);
          sacc[kb] = __builtin_amdgcn_mfma_f32_32x32x16_bf16(kf, qf[db],
                                                             sacc[kb], 0, 0, 0);
        }

      float p[2][16];
#pragma unroll
      for (int kb = 0; kb < 2; ++kb)
#pragma unroll
        for (int r = 0; r < 16; ++r) p[kb][r] = sacc[kb][r];

      if (k0 + 63 > qw) {  // mask only on diagonal-crossing tiles
        const int qg = qw + q31;
#pragma unroll
        for (int kb = 0; kb < 2; ++kb)
#pragma unroll
          for (int r = 0; r < 16; ++r) {
            const int k = k0 + kb * 32 + (r & 3) + 8 * (r >> 2) + 4 * hw;
            if (k > qg) p[kb][r] = -1e30f;
          }
      }

      // row max: in-lane over 32 values + cross-half exchange
      float mt = p[0][0];
#pragma unroll
      for (int r = 1; r < 16; ++r) mt = fmaxf(mt, p[0][r]);
#pragma unroll
      for (int r = 0; r < 16; ++r) mt = fmaxf(mt, p[1][r]);
      mt = fmaxf(mt, __shfl_xor(mt, 32));

      // defer-max: rescale only when the max grew past threshold (log2 units)
      if (__any(mt > mrow + 11.5f)) {
        const float mnew = fmaxf(mrow, mt);
        const float alpha = fast_exp2(mrow - mnew);
        mrow = mnew;
        lsum *= alpha;
        float areg[16];
#pragma unroll
        for (int r = 0; r < 16; ++r) {
          const int qloc = (r & 3) + 8 * (r >> 2) + 4 * hw;
          areg[r] = __shfl(alpha, qloc + (lane & 32));
        }
#pragma unroll
        for (int db = 0; db < 4; ++db)
#pragma unroll
          for (int r = 0; r < 16; ++r) acc[db][r] *= areg[r];
      }

      // P = 2^(S - m), row sum in-lane + cross-half
      float rs = 0.f;
#pragma unroll
      for (int kb = 0; kb < 2; ++kb)
#pragma unroll
        for (int r = 0; r < 16; ++r) {
          const float pe = fast_exp2(p[kb][r] - mrow);
          p[kb][r] = pe;
          rs += pe;
        }
      rs += __shfl_xor(rs, 32);
      lsum += rs;

      // pack P to bf16 pairs: pk[kb][i] = (p[2i], p[2i+1])
      unsigned int pk[2][8];
#pragma unroll
      for (int kb = 0; kb < 2; ++kb)
#pragma unroll
        for (int i = 0; i < 8; ++i)
          asm("v_cvt_pk_bf16_f32 %0, %1, %2"
              : "=v"(pk[kb][i])
              : "v"(p[kb][2 * i]), "v"(p[kb][2 * i + 1]));

      // PV: A-frag kb16 via 2 permlane32_swap; B = V^T chunks (conflict-free)
#pragma unroll
      for (int kb16 = 0; kb16 < 4; ++kb16) {
        const int kb = kb16 >> 1;
        const int j0 = (kb16 & 1) * 4;
        unsigned int a0 = pk[kb][j0 + 0], b0 = pk[kb][j0 + 2];
        unsigned int a1 = pk[kb][j0 + 1], b1 = pk[kb][j0 + 3];
        asm volatile("v_permlane32_swap_b32 %0, %1" : "+v"(a0), "+v"(b0));
        asm volatile("v_permlane32_swap_b32 %0, %1" : "+v"(a1), "+v"(b1));
        u32x4 afu;
        afu.x = a0; afu.y = a1; afu.z = b0; afu.w = b1;
        bf16x8 pa;
        __builtin_memcpy(&pa, &afu, 16);
#pragma unroll
        for (int db = 0; db < 4; ++db) {
          // chunk (kgl, d): kgl = kb16*2 + hw, d = db*32 + q31
          const int kgl = kb16 * 2 + hw;
          const int d = db * 32 + q31;
          bf16x8 vf = *reinterpret_cast<const bf16x8*>(
              (const char*)Vtl + (kgl * 128 + d) * 16);
          acc[db] = __builtin_amdgcn_mfma_f32_32x32x16_bf16(pa, vf,
                                                            acc[db], 0, 0, 0);
        }
      }
    }

    __builtin_amdgcn_sched_barrier(0);
    __builtin_amdgcn_s_barrier();  // B: all reads of tile t done
  }

  // epilogue: translate per-q lsum to per-reg, normalize, store
  const float inv = 1.0f / lsum;
  float invq[16];
#pragma unroll
  for (int r = 0; r < 16; ++r) {
    const int qloc = (r & 3) + 8 * (r >> 2) + 4 * hw;
    invq[r] = __shfl(inv, qloc + (lane & 32));
  }
#pragma unroll
  for (int db = 0; db < 4; ++db)
#pragma unroll
    for (int r = 0; r < 16; ++r) {
      const int qg = qw + (r & 3) + 8 * (r >> 2) + 4 * hw;
      const int dg = db * 32 + q31;
      Og[((size_t)(b * 2048 + qg)) * 2048 + h * 128 + dg] =
          __float2bfloat16(acc[db][r] * invq[r]);
    }
}

// ---------------- launcher ----------------------------------------------------
extern "C" void kernel_launch(void* const* d_in, const int* in_sizes, int n_in,
                              void* d_out, int out_size, void* d_ws,
                              size_t ws_size, hipStream_t stream) {
  const float* hidden = (const float*)d_in[0];
  const float* cs = (const float*)d_in[1];
  const float* sn = (const float*)d_in[2];
  const float* wqkv = (const float*)d_in[3];
  const float* wo = (const float*)d_in[4];
  float* out = (float*)d_out;

  bf16* p = (bf16*)d_ws;
  bf16* hid_b = p;   p += 8388608;   // reused later as attn out
  bf16* wqkv_b = p;  p += 6291456;
  bf16* wo_b = p;    p += 4194304;
  bf16* qkv = p;     p += 12582912;  // [4096][3072] pre-RoPE
  bf16* Qs = p;      p += 8388608;   // [2][16][2048][128] (pre-scaled)
  bf16* Ksc = p;     p += 2097152;   // [2][4][2048][128]
  bf16* Vt = p;      p += 2097152;   // [2][4] k-grouped V^T (128x2048)

  // allow >64KiB dynamic LDS for the 8-phase kernels (idempotent, capture-safe)
  (void)hipFuncSetAttribute((const void*)gemm256<192, bf16>,
                            hipFuncAttributeMaxDynamicSharedMemorySize, 131072);
  (void)hipFuncSetAttribute((const void*)gemm256<128, float>,
                            hipFuncAttributeMaxDynamicSharedMemorySize, 131072);

  cast3<<<2048, 256, 0, stream>>>(hidden, wqkv, wo, hid_b, wqkv_b, wo_b);

  // QKV: M=4096, N=3072, K=2048; BN=192 -> 16x16 = 256 blocks (full fill)
  gemm256<192, bf16><<<256, 512, 114688, stream>>>(hid_b, wqkv_b, qkv,
                                                   4096, 3072, 2048, 16);
  rope_vtrans<<<4352, 256, 0, stream>>>(qkv, cs, sn, Qs, Ksc, Vt);

  bf16* aout = hid_b;
  attn_fwd<<<512, 256, 0, stream>>>(Qs, Ksc, Vt, aout);

  // out-proj: M=4096, N=2048, K=2048; BN=128 -> 16x16 = 256 blocks (full fill)
  gemm256<128, float><<<256, 512, 98304, stream>>>(aout, wo_b, out,
                                                   4096, 2048, 2048, 16);
}